// Round 4
// baseline (679.645 us; speedup 1.0000x reference)
//
#include <hip/hip_runtime.h>
#include <math.h>

#define XD 32
#define HD 128

typedef float f32x16 __attribute__((ext_vector_type(16)));
typedef int v2i __attribute__((ext_vector_type(2)));

#if __has_builtin(__builtin_amdgcn_cvt_pk_fp8_f32)
#define HAVE_CVT_FP8 1
#endif

// ---- scalar f32 -> e4m3fn (RNE), used by prep (and kernel fallback) ----
static __device__ __forceinline__ unsigned char f2e4m3(float f){
  if (!(f==f)) return 0x7F;
  unsigned u = __float_as_uint(f);
  unsigned s = (u>>24)&0x80;
  float a = fabsf(f);
  if (a >= 464.f) return (unsigned char)(s|0x7E);           // clamp to 448
  if (a < 0.0009765625f) return (unsigned char)s;            // < 2^-10 -> 0
  int e = (int)((u>>23)&0xFF) - 127;
  if (e < -6){                                               // subnormal, ulp=2^-9
    int m = (int)rintf(ldexpf(a, 9));
    if (m >= 8) return (unsigned char)(s|0x08);
    return (unsigned char)(s|(unsigned)m);
  }
  int m = (int)rintf(ldexpf(a, 3-e));                        // in [8,16]
  if (m == 16){ ++e; m = 8; }
  if (e > 8) return (unsigned char)(s|0x7E);
  return (unsigned char)(s | (unsigned)((e+7)<<3) | (unsigned)(m-8));
}

template<bool HI>
static __device__ __forceinline__ int cvtpk_fp8(float a, float b, int old){
#ifdef HAVE_CVT_FP8
  return __builtin_amdgcn_cvt_pk_fp8_f32(a, b, old, HI);
#else
  int w = (int)f2e4m3(a) | ((int)f2e4m3(b) << 8);
  return HI ? ((old & 0x0000FFFF) | (w << 16)) : ((old & (int)0xFFFF0000) | w);
#endif
}

// exchange halves: new_x[l] = l<32 ? x[l] : y[l-32]; new_y[l] = l<32 ? x[l+32] : y[l]
static __device__ __forceinline__ void plswap(int &x, int &y){
#if __has_builtin(__builtin_amdgcn_permlane32_swap)
  v2i r = __builtin_amdgcn_permlane32_swap(x, y, false, false);
  x = r[0]; y = r[1];
#else
  unsigned lane = threadIdx.x & 63u;
  int sx = __shfl_xor(x, 32, 64);
  int sy = __shfl_xor(y, 32, 64);
  int nx = (lane < 32) ? x : sy;
  int ny = (lane < 32) ? sx : y;
  x = nx; y = ny;
#endif
}

// One K=16 fp8 B-frag (as long) from a 32x32 f32 C tile, relu applied.
// C: feat=(r&3)+8*(r>>2)+4*half, batch=lane&31.  B: col=lane&31, k=(l>>5)*8+j (byte j).
template<int KT>
static __device__ __forceinline__ long c2b_kt(const f32x16 &c){
  int P0 = cvtpk_fp8<false>(fmaxf(c[8*KT+0],0.f), fmaxf(c[8*KT+1],0.f), 0);
  P0     = cvtpk_fp8<true >(fmaxf(c[8*KT+2],0.f), fmaxf(c[8*KT+3],0.f), P0);
  int P1 = cvtpk_fp8<false>(fmaxf(c[8*KT+4],0.f), fmaxf(c[8*KT+5],0.f), 0);
  P1     = cvtpk_fp8<true >(fmaxf(c[8*KT+6],0.f), fmaxf(c[8*KT+7],0.f), P1);
  plswap(P0, P1);
  return (long)(((unsigned long)(unsigned)P0) | ((unsigned long)(unsigned)P1 << 32));
}

static __device__ __forceinline__ void ld8(const float* __restrict__ p, float* dst){
  float4 a = *(const float4*)p, b = *(const float4*)(p+4);
  dst[0]=a.x; dst[1]=a.y; dst[2]=a.z; dst[3]=a.w;
  dst[4]=b.x; dst[5]=b.y; dst[6]=b.z; dst[7]=b.w;
}

// bias C-frag gather: element rg*4+q <- p[rg*8 + half*4 + q]
static __device__ __forceinline__ f32x16 load_bias16(const float* __restrict__ p, int half){
  f32x16 bv;
#pragma unroll
  for (int rg=0; rg<4; ++rg){
    const float4 t = *(const float4*)(p + rg*8 + half*4);
    bv[rg*4+0]=t.x; bv[rg*4+1]=t.y; bv[rg*4+2]=t.z; bv[rg*4+3]=t.w;
  }
  return bv;
}

// ---- prep: pack weights as fp8 A-frags (scaled); scaled biases as f32 ----
// A-frag (32x32x16 fp8): lane l holds row=l&31 (+fo*32), k=(l>>5)*8+j at byte j.
// scales: A_in=8*Wi (z col at dead diag slot); A1=8*W1; A2=8*W2.
// bi8 = 8*bi ; b1s = 64*b1 ; b2s = 512*b2  (bias enters as first-MFMA C operand)
__global__ void prep(const float* __restrict__ Wi, const float* __restrict__ bi,
                     const float* __restrict__ W1, const float* __restrict__ b1,
                     const float* __restrict__ W2, const float* __restrict__ b2,
                     const float* __restrict__ M,
                     unsigned char* __restrict__ wip, unsigned char* __restrict__ w1p,
                     unsigned char* __restrict__ w2p, float* __restrict__ Mt,
                     float* __restrict__ bi8, float* __restrict__ b1s,
                     float* __restrict__ b2s){
  int b = (int)blockIdx.x;
  int l = (int)threadIdx.x;
  int h = l >> 5, cl = l & 31;
  if (b < 256){                       // wip: frag idx = i*8 + kt*4 + fo
    int i = b >> 3, kt = (b >> 2) & 1, fo = b & 3;
    int row = fo*32 + cl;
    unsigned char bytes[8];
#pragma unroll
    for (int j = 0; j < 8; ++j){
      int k = kt*16 + h*8 + j;
      int src = (k == i) ? XD : k;
      bytes[j] = f2e4m3(8.f * Wi[((size_t)i*HD + row)*(XD+1) + src]);
    }
    long v8; __builtin_memcpy(&v8, bytes, 8);
    *(long*)(wip + ((size_t)b*64 + l)*8) = v8;
  } else if (b < 320){                // w1p/w2p: frag idx = kt*4 + fo
    const float* W = (b < 288) ? W1 : W2;
    unsigned char* dp = (b < 288) ? w1p : w2p;
    int f = (b - 256) & 31, kt = f >> 2, fo = f & 3;
    int row = fo*32 + cl;
    unsigned char bytes[8];
#pragma unroll
    for (int j = 0; j < 8; ++j)
      bytes[j] = f2e4m3(8.f * W[(size_t)row*HD + kt*16 + h*8 + j]);
    long v8; __builtin_memcpy(&v8, bytes, 8);
    *(long*)(dp + ((size_t)f*64 + l)*8) = v8;
  } else if (b == 320){               // M transpose
#pragma unroll
    for (int t = 0; t < 16; ++t){
      int idx = t*64 + l;
      int i = idx >> 5, k = idx & 31;
      Mt[i*32 + k] = M[k*32 + i];
    }
  } else {                            // scaled biases
    for (int t = 0; t < 64; ++t){
      int idx = t*64 + l;
      bi8[idx] = 8.f * bi[idx];
    }
#pragma unroll
    for (int t = 0; t < 2; ++t){
      b1s[t*64 + l] = 64.f  * b1[t*64 + l];
      b2s[t*64 + l] = 512.f * b2[t*64 + l];
    }
  }
}

// ---- main kernel: 2048 blocks x 64 threads; wave owns 32 rows; 2 waves/SIMD ----
__global__ void __launch_bounds__(64, 2)
genkern(const float* __restrict__ x, const float* __restrict__ z,
        const float* __restrict__ wf, const float* __restrict__ bf,
        const unsigned char* __restrict__ wip, const unsigned char* __restrict__ w1p,
        const unsigned char* __restrict__ w2p, const float* __restrict__ Mt,
        const float* __restrict__ bi8, const float* __restrict__ b1s,
        const float* __restrict__ b2s, float* __restrict__ out)
{
  const int lane = (int)threadIdx.x;
  const int half = lane >> 5, col = lane & 31;
  const long rbase = (long)blockIdx.x * 32;

  // resident weight frags (fp8): 8 kt x 4 fo each
  long w1f[8][4], w2f[8][4];
#pragma unroll
  for (int kt = 0; kt < 8; ++kt)
#pragma unroll
    for (int fo = 0; fo < 4; ++fo){
      w1f[kt][fo] = *(const long*)(w1p + (((size_t)(kt*4+fo))*64 + lane)*8);
      w2f[kt][fo] = *(const long*)(w2p + (((size_t)(kt*4+fo))*64 + lane)*8);
    }

  // out-state: lane(half h) holds k = kt*16 + h*8 + j at slot kt*8+j
  float st[16];
#pragma unroll
  for (int kt = 0; kt < 2; ++kt)
    ld8(x + (rbase + col)*XD + kt*16 + half*8, &st[kt*8]);

  for (int i = 0; i < XD; ++i){
    // per-step Wi frags: global (L2-hot) -> VGPR
    long wif[2][4];
#pragma unroll
    for (int kt = 0; kt < 2; ++kt)
#pragma unroll
      for (int fo = 0; fo < 4; ++fo)
        wif[kt][fo] = *(const long*)(wip + (((size_t)((i*8)+kt*4+fo))*64 + lane)*8);

    float mtv[2][8];
#pragma unroll
    for (int kt = 0; kt < 2; ++kt)
      ld8(Mt + i*32 + kt*16 + half*8, &mtv[kt][0]);

    float zvv = z[(rbase + col)*XD + i];

    // x_masked B-frags from state (fp8 pack); z injected after
    int xbi[2][2];
#pragma unroll
    for (int kt = 0; kt < 2; ++kt)
#pragma unroll
      for (int d = 0; d < 2; ++d){
        float v0 = st[kt*8+4*d+0]*mtv[kt][4*d+0];
        float v1 = st[kt*8+4*d+1]*mtv[kt][4*d+1];
        float v2 = st[kt*8+4*d+2]*mtv[kt][4*d+2];
        float v3 = st[kt*8+4*d+3]*mtv[kt][4*d+3];
        int w = cvtpk_fp8<false>(v0, v1, 0);
        xbi[kt][d] = cvtpk_fp8<true>(v2, v3, w);
      }
    // z byte-splice at k==i (uniform dword select + half-match cndmask)
    const int hmi = (i>>3)&1;
    const bool hm = (half == hmi);
    {
      const int kti = i>>4, di = (i>>2)&1, sh = 8*(i&3);
      const int msk = ~(0xFF << sh);
      int pz = cvtpk_fp8<false>(zvv, 0.f, 0) & 0xFF;
      int ins = pz << sh;
#pragma unroll
      for (int kt = 0; kt < 2; ++kt)
#pragma unroll
        for (int d = 0; d < 2; ++d)
          if (kt == kti && d == di){
            int mod = (xbi[kt][d] & msk) | ins;
            xbi[kt][d] = hm ? mod : xbi[kt][d];
          }
    }
    long xb[2];
#pragma unroll
    for (int kt = 0; kt < 2; ++kt)
      xb[kt] = (long)(((unsigned long)(unsigned)xbi[kt][0]) |
                      ((unsigned long)(unsigned)xbi[kt][1] << 32));

    // input layer: K=32, bias as C of first MFMA
    f32x16 acc[4];
#pragma unroll
    for (int fo = 0; fo < 4; ++fo)
      acc[fo] = __builtin_amdgcn_mfma_f32_32x32x16_fp8_fp8(
                  wif[0][fo], xb[0], load_bias16(bi8 + (size_t)i*HD + fo*32, half), 0,0,0);
#pragma unroll
    for (int fo = 0; fo < 4; ++fo)
      acc[fo] = __builtin_amdgcn_mfma_f32_32x32x16_fp8_fp8(wif[1][fo], xb[1], acc[fo], 0,0,0);

    // h1 -> fp8 B-frags
    long hb[8];
#pragma unroll
    for (int fo = 0; fo < 4; ++fo){
      hb[fo*2+0] = c2b_kt<0>(acc[fo]);
      hb[fo*2+1] = c2b_kt<1>(acc[fo]);
    }

    // layer 1: K=128, bias C-init
    f32x16 a2[4];
#pragma unroll
    for (int fo = 0; fo < 4; ++fo)
      a2[fo] = __builtin_amdgcn_mfma_f32_32x32x16_fp8_fp8(
                 w1f[0][fo], hb[0], load_bias16(b1s + fo*32, half), 0,0,0);
#pragma unroll
    for (int kt = 1; kt < 8; ++kt)
#pragma unroll
      for (int fo = 0; fo < 4; ++fo)
        a2[fo] = __builtin_amdgcn_mfma_f32_32x32x16_fp8_fp8(w1f[kt][fo], hb[kt], a2[fo], 0,0,0);

#pragma unroll
    for (int fo = 0; fo < 4; ++fo){
      hb[fo*2+0] = c2b_kt<0>(a2[fo]);
      hb[fo*2+1] = c2b_kt<1>(a2[fo]);
    }

    // layer 2: K=128, bias C-init
#pragma unroll
    for (int fo = 0; fo < 4; ++fo)
      acc[fo] = __builtin_amdgcn_mfma_f32_32x32x16_fp8_fp8(
                  w2f[0][fo], hb[0], load_bias16(b2s + fo*32, half), 0,0,0);
#pragma unroll
    for (int kt = 1; kt < 8; ++kt)
#pragma unroll
      for (int fo = 0; fo < 4; ++fo)
        acc[fo] = __builtin_amdgcn_mfma_f32_32x32x16_fp8_fp8(w2f[kt][fo], hb[kt], acc[fo], 0,0,0);

    // epilogue: val = sigmoid((relu(h3') . wf)/512 + bf)   (h3' is 512x-scaled)
    float part = 0.f;
#pragma unroll
    for (int fo = 0; fo < 4; ++fo){
      const float* wp = wf + (size_t)i*HD + fo*32;
#pragma unroll
      for (int rg = 0; rg < 4; ++rg){
        const float4 t = *(const float4*)(wp + rg*8 + half*4);
        part += fmaxf(acc[fo][rg*4+0], 0.f) * t.x;
        part += fmaxf(acc[fo][rg*4+1], 0.f) * t.y;
        part += fmaxf(acc[fo][rg*4+2], 0.f) * t.z;
        part += fmaxf(acc[fo][rg*4+3], 0.f) * t.w;
      }
    }
    float tt = part + __shfl_xor(part, 32, 64);
    float val = 1.f/(1.f + __expf(-(tt*(1.f/512.f) + bf[i])));

    // state update: column i lives at slot (i>>4)*8+(i&7) on half (i>>3)&1
    const int slot_i = ((i>>4)<<3) | (i&7);
#pragma unroll
    for (int s = 0; s < 16; ++s)
      if (s == slot_i)
        st[s] = hm ? val : st[s];
  }

  // write out
#pragma unroll
  for (int kt = 0; kt < 2; ++kt){
    float* p = out + (rbase + col)*XD + kt*16 + half*8;
    float4 a, b;
    a.x = st[kt*8+0]; a.y = st[kt*8+1]; a.z = st[kt*8+2]; a.w = st[kt*8+3];
    b.x = st[kt*8+4]; b.y = st[kt*8+5]; b.z = st[kt*8+6]; b.w = st[kt*8+7];
    *(float4*)p = a;
    *(float4*)(p+4) = b;
  }
}

extern "C" void kernel_launch(void* const* d_in, const int* in_sizes, int n_in,
                              void* d_out, int out_size, void* d_ws, size_t ws_size,
                              hipStream_t stream){
  (void)in_sizes; (void)n_in; (void)out_size; (void)ws_size;
  const float* x  = (const float*)d_in[0];
  const float* z  = (const float*)d_in[1];
  const float* M  = (const float*)d_in[2];
  const float* Wi = (const float*)d_in[3];
  const float* bi = (const float*)d_in[4];
  const float* wf = (const float*)d_in[5];
  const float* bf = (const float*)d_in[6];
  const float* W1 = (const float*)d_in[7];
  const float* b1 = (const float*)d_in[8];
  const float* W2 = (const float*)d_in[9];
  const float* b2 = (const float*)d_in[10];

  unsigned char* wip = (unsigned char*)d_ws;            // 256*512 = 131072
  unsigned char* w1p = wip + 131072;                    // 32*512 = 16384
  unsigned char* w2p = w1p + 16384;                     // 16384
  float*         Mt  = (float*)(w2p + 16384);           // 4096
  float*         bi8 = Mt + 1024;                       // 32*128*4 = 16384
  float*         b1s = bi8 + 4096;                      // 512
  float*         b2s = b1s + 128;                       // 512

  prep<<<dim3(322), dim3(64), 0, stream>>>(Wi, bi, W1, b1, W2, b2, M,
                                           wip, w1p, w2p, Mt, bi8, b1s, b2s);
  genkern<<<dim3(2048), dim3(64), 0, stream>>>(x, z, wf, bf, wip, w1p, w2p, Mt,
                                               bi8, b1s, b2s, (float*)d_out);
}

// Round 5
// 186.146 us; speedup vs baseline: 3.6511x; 3.6511x over previous
//
#include <hip/hip_runtime.h>
#include <math.h>

#define XD 32
#define HD 128

typedef float f32x16 __attribute__((ext_vector_type(16)));
typedef int v2i __attribute__((ext_vector_type(2)));

#if __has_builtin(__builtin_amdgcn_cvt_pk_fp8_f32)
#define HAVE_CVT_FP8 1
#endif

// ---- scalar f32 -> e4m3fn (RNE), used by prep (and kernel fallback) ----
static __device__ __forceinline__ unsigned char f2e4m3(float f){
  if (!(f==f)) return 0x7F;
  unsigned u = __float_as_uint(f);
  unsigned s = (u>>24)&0x80;
  float a = fabsf(f);
  if (a >= 464.f) return (unsigned char)(s|0x7E);           // clamp to 448
  if (a < 0.0009765625f) return (unsigned char)s;            // < 2^-10 -> 0
  int e = (int)((u>>23)&0xFF) - 127;
  if (e < -6){                                               // subnormal, ulp=2^-9
    int m = (int)rintf(ldexpf(a, 9));
    if (m >= 8) return (unsigned char)(s|0x08);
    return (unsigned char)(s|(unsigned)m);
  }
  int m = (int)rintf(ldexpf(a, 3-e));                        // in [8,16]
  if (m == 16){ ++e; m = 8; }
  if (e > 8) return (unsigned char)(s|0x7E);
  return (unsigned char)(s | (unsigned)((e+7)<<3) | (unsigned)(m-8));
}

template<bool HI>
static __device__ __forceinline__ int cvtpk_fp8(float a, float b, int old){
#ifdef HAVE_CVT_FP8
  return __builtin_amdgcn_cvt_pk_fp8_f32(a, b, old, HI);
#else
  int w = (int)f2e4m3(a) | ((int)f2e4m3(b) << 8);
  return HI ? ((old & 0x0000FFFF) | (w << 16)) : ((old & (int)0xFFFF0000) | w);
#endif
}

// exchange halves: new_x[l] = l<32 ? x[l] : y[l-32]; new_y[l] = l<32 ? x[l+32] : y[l]
static __device__ __forceinline__ void plswap(int &x, int &y){
#if __has_builtin(__builtin_amdgcn_permlane32_swap)
  v2i r = __builtin_amdgcn_permlane32_swap(x, y, false, false);
  x = r[0]; y = r[1];
#else
  unsigned lane = threadIdx.x & 63u;
  int sx = __shfl_xor(x, 32, 64);
  int sy = __shfl_xor(y, 32, 64);
  int nx = (lane < 32) ? x : sy;
  int ny = (lane < 32) ? sx : y;
  x = nx; y = ny;
#endif
}

// One K=16 fp8 B-frag (as long) from a 32x32 f32 C tile, relu applied.
// C: feat=(r&3)+8*(r>>2)+4*half, batch=lane&31.  B: col=lane&31, k=(l>>5)*8+j (byte j).
template<int KT>
static __device__ __forceinline__ long c2b_kt(const f32x16 &c){
  int P0 = cvtpk_fp8<false>(fmaxf(c[8*KT+0],0.f), fmaxf(c[8*KT+1],0.f), 0);
  P0     = cvtpk_fp8<true >(fmaxf(c[8*KT+2],0.f), fmaxf(c[8*KT+3],0.f), P0);
  int P1 = cvtpk_fp8<false>(fmaxf(c[8*KT+4],0.f), fmaxf(c[8*KT+5],0.f), 0);
  P1     = cvtpk_fp8<true >(fmaxf(c[8*KT+6],0.f), fmaxf(c[8*KT+7],0.f), P1);
  plswap(P0, P1);
  return (long)(((unsigned long)(unsigned)P0) | ((unsigned long)(unsigned)P1 << 32));
}

static __device__ __forceinline__ void ld8(const float* __restrict__ p, float* dst){
  float4 a = *(const float4*)p, b = *(const float4*)(p+4);
  dst[0]=a.x; dst[1]=a.y; dst[2]=a.z; dst[3]=a.w;
  dst[4]=b.x; dst[5]=b.y; dst[6]=b.z; dst[7]=b.w;
}

// bias C-frag gather: element rg*4+q <- p[rg*8 + half*4 + q]
static __device__ __forceinline__ f32x16 load_bias16(const float* __restrict__ p, int half){
  f32x16 bv;
#pragma unroll
  for (int rg=0; rg<4; ++rg){
    const float4 t = *(const float4*)(p + rg*8 + half*4);
    bv[rg*4+0]=t.x; bv[rg*4+1]=t.y; bv[rg*4+2]=t.z; bv[rg*4+3]=t.w;
  }
  return bv;
}

// ---- prep: pack weights as fp8 A-frags (scaled); scaled biases as f32 ----
// A-frag (32x32x16 fp8): lane l holds row=l&31 (+fo*32), k=(l>>5)*8+j at byte j.
// scales: 8*Wi (z col at dead diag slot); 8*W1; 8*W2; wf frags = 64*wf (row 0 only).
// bi8 = 8*bi ; b1s = 64*b1 ; b2s = 512*b2  (bias enters as first-MFMA C operand)
__global__ void prep(const float* __restrict__ Wi, const float* __restrict__ bi,
                     const float* __restrict__ W1, const float* __restrict__ b1,
                     const float* __restrict__ W2, const float* __restrict__ b2,
                     const float* __restrict__ M,  const float* __restrict__ wf,
                     unsigned char* __restrict__ wip, unsigned char* __restrict__ w1p,
                     unsigned char* __restrict__ w2p, unsigned char* __restrict__ wfp,
                     float* __restrict__ Mt, float* __restrict__ bi8,
                     float* __restrict__ b1s, float* __restrict__ b2s){
  int b = (int)blockIdx.x;
  int l = (int)threadIdx.x;
  int h = l >> 5, cl = l & 31;
  if (b < 256){                       // wip: frag idx = i*8 + kt*4 + fo
    int i = b >> 3, kt = (b >> 2) & 1, fo = b & 3;
    int row = fo*32 + cl;
    unsigned char bytes[8];
#pragma unroll
    for (int j = 0; j < 8; ++j){
      int k = kt*16 + h*8 + j;
      int src = (k == i) ? XD : k;
      bytes[j] = f2e4m3(8.f * Wi[((size_t)i*HD + row)*(XD+1) + src]);
    }
    long v8; __builtin_memcpy(&v8, bytes, 8);
    *(long*)(wip + ((size_t)b*64 + l)*8) = v8;
  } else if (b < 320){                // w1p/w2p: frag idx = kt*4 + fo
    const float* W = (b < 288) ? W1 : W2;
    unsigned char* dp = (b < 288) ? w1p : w2p;
    int f = (b - 256) & 31, kt = f >> 2, fo = f & 3;
    int row = fo*32 + cl;
    unsigned char bytes[8];
#pragma unroll
    for (int j = 0; j < 8; ++j)
      bytes[j] = f2e4m3(8.f * W[(size_t)row*HD + kt*16 + h*8 + j]);
    long v8; __builtin_memcpy(&v8, bytes, 8);
    *(long*)(dp + ((size_t)f*64 + l)*8) = v8;
  } else if (b < 576){                // wfp: frag idx = i*8 + kt, row0 = 64*wf_i
    int f = b - 320;
    int i = f >> 3, kt = f & 7;
    unsigned char bytes[8];
#pragma unroll
    for (int j = 0; j < 8; ++j){
      float v = (cl == 0) ? 64.f * wf[(size_t)i*HD + kt*16 + h*8 + j] : 0.f;
      bytes[j] = f2e4m3(v);
    }
    long v8; __builtin_memcpy(&v8, bytes, 8);
    *(long*)(wfp + ((size_t)f*64 + l)*8) = v8;
  } else if (b == 576){               // M transpose
#pragma unroll
    for (int t = 0; t < 16; ++t){
      int idx = t*64 + l;
      int i = idx >> 5, k = idx & 31;
      Mt[i*32 + k] = M[k*32 + i];
    }
  } else {                            // scaled biases
    for (int t = 0; t < 64; ++t){
      int idx = t*64 + l;
      bi8[idx] = 8.f * bi[idx];
    }
#pragma unroll
    for (int t = 0; t < 2; ++t){
      b1s[t*64 + l] = 64.f  * b1[t*64 + l];
      b2s[t*64 + l] = 512.f * b2[t*64 + l];
    }
  }
}

struct Pref {
  long wif[2][4];   // input-layer A-frags, step i
  long wfa[8];      // wf A-frags, step i
  float zv[2];      // z values, step i
};

static __device__ __forceinline__ void issue_pref(int i, int lane, long rbase, int col,
                     const unsigned char* __restrict__ wip,
                     const unsigned char* __restrict__ wfp,
                     const float* __restrict__ z, Pref& p){
#pragma unroll
  for (int kt = 0; kt < 2; ++kt)
#pragma unroll
    for (int fo = 0; fo < 4; ++fo)
      p.wif[kt][fo] = *(const long*)(wip + (((size_t)(i*8 + kt*4 + fo))*64 + lane)*8);
#pragma unroll
  for (int kt = 0; kt < 8; ++kt)
    p.wfa[kt] = *(const long*)(wfp + (((size_t)(i*8 + kt))*64 + lane)*8);
  p.zv[0] = z[(rbase + col)*XD + i];
  p.zv[1] = z[(rbase + 32 + col)*XD + i];
}

static __device__ __forceinline__ void stepfn(int i, int lane, int half, int col, long rbase,
    const float* __restrict__ Mt, const float* __restrict__ bi8,
    const float* __restrict__ b1s, const float* __restrict__ b2s,
    const float* __restrict__ bf,
    const unsigned char* __restrict__ wip, const unsigned char* __restrict__ wfp,
    const float* __restrict__ z,
    const long (&w1f)[8][4], const long (&w2f)[8][4],
    float (&st)[2][16], Pref& cur, Pref& nxt)
{
  // prefetch step i+1 (wraps at 31 -> 0, harmless)
  issue_pref((i + 1) & (XD - 1), lane, rbase, col, wip, wfp, z, nxt);

  // in-step loads (L1/L2-hot): bias C-frags, M column
  f32x16 bic[4];
#pragma unroll
  for (int fo = 0; fo < 4; ++fo)
    bic[fo] = load_bias16(bi8 + (size_t)i*HD + fo*32, half);

  float mtv[2][8];
#pragma unroll
  for (int kt = 0; kt < 2; ++kt)
    ld8(Mt + i*32 + kt*16 + half*8, &mtv[kt][0]);

  // x_masked B-frags from state (fp8 pack); z injected after
  int xbi[2][2][2];
#pragma unroll
  for (int bt = 0; bt < 2; ++bt)
#pragma unroll
    for (int kt = 0; kt < 2; ++kt)
#pragma unroll
      for (int d = 0; d < 2; ++d){
        float v0 = st[bt][kt*8+4*d+0]*mtv[kt][4*d+0];
        float v1 = st[bt][kt*8+4*d+1]*mtv[kt][4*d+1];
        float v2 = st[bt][kt*8+4*d+2]*mtv[kt][4*d+2];
        float v3 = st[bt][kt*8+4*d+3]*mtv[kt][4*d+3];
        int w = cvtpk_fp8<false>(v0, v1, 0);
        xbi[bt][kt][d] = cvtpk_fp8<true>(v2, v3, w);
      }
  // z byte-splice at k==i (uniform dword select + half-match cndmask)
  const int hmi = (i>>3)&1;
  const bool hm = (half == hmi);
  {
    const int kti = i>>4, di = (i>>2)&1, sh = 8*(i&3);
    const int msk = ~(0xFF << sh);
#pragma unroll
    for (int bt = 0; bt < 2; ++bt){
      int pz = cvtpk_fp8<false>(cur.zv[bt], 0.f, 0) & 0xFF;
      int ins = pz << sh;
#pragma unroll
      for (int kt = 0; kt < 2; ++kt)
#pragma unroll
        for (int d = 0; d < 2; ++d)
          if (kt == kti && d == di){
            int mod = (xbi[bt][kt][d] & msk) | ins;
            xbi[bt][kt][d] = hm ? mod : xbi[bt][kt][d];
          }
    }
  }
  long xb[2][2];
#pragma unroll
  for (int bt = 0; bt < 2; ++bt)
#pragma unroll
    for (int kt = 0; kt < 2; ++kt)
      xb[bt][kt] = (long)(((unsigned long)(unsigned)xbi[bt][kt][0]) |
                          ((unsigned long)(unsigned)xbi[bt][kt][1] << 32));

  // input layer: K=32, bias as C of first MFMA
  f32x16 acc[4][2];
#pragma unroll
  for (int fo = 0; fo < 4; ++fo)
#pragma unroll
    for (int bt = 0; bt < 2; ++bt)
      acc[fo][bt] = __builtin_amdgcn_mfma_f32_32x32x16_fp8_fp8(
                      cur.wif[0][fo], xb[bt][0], bic[fo], 0,0,0);
#pragma unroll
  for (int fo = 0; fo < 4; ++fo)
#pragma unroll
    for (int bt = 0; bt < 2; ++bt)
      acc[fo][bt] = __builtin_amdgcn_mfma_f32_32x32x16_fp8_fp8(
                      cur.wif[1][fo], xb[bt][1], acc[fo][bt], 0,0,0);

  // h1 -> fp8 B-frags
  long hb[2][8];
#pragma unroll
  for (int fo = 0; fo < 4; ++fo)
#pragma unroll
    for (int bt = 0; bt < 2; ++bt){
      hb[bt][fo*2+0] = c2b_kt<0>(acc[fo][bt]);
      hb[bt][fo*2+1] = c2b_kt<1>(acc[fo][bt]);
    }

  // layer 1: K=128, bias C-init
  f32x16 a2[4][2];
#pragma unroll
  for (int fo = 0; fo < 4; ++fo){
    f32x16 b1c = load_bias16(b1s + fo*32, half);
#pragma unroll
    for (int bt = 0; bt < 2; ++bt)
      a2[fo][bt] = __builtin_amdgcn_mfma_f32_32x32x16_fp8_fp8(
                     w1f[0][fo], hb[bt][0], b1c, 0,0,0);
  }
#pragma unroll
  for (int kt = 1; kt < 8; ++kt)
#pragma unroll
    for (int fo = 0; fo < 4; ++fo)
#pragma unroll
      for (int bt = 0; bt < 2; ++bt)
        a2[fo][bt] = __builtin_amdgcn_mfma_f32_32x32x16_fp8_fp8(
                       w1f[kt][fo], hb[bt][kt], a2[fo][bt], 0,0,0);

#pragma unroll
  for (int fo = 0; fo < 4; ++fo)
#pragma unroll
    for (int bt = 0; bt < 2; ++bt){
      hb[bt][fo*2+0] = c2b_kt<0>(a2[fo][bt]);
      hb[bt][fo*2+1] = c2b_kt<1>(a2[fo][bt]);
    }

  // layer 2: K=128, bias C-init (reuse acc)
#pragma unroll
  for (int fo = 0; fo < 4; ++fo){
    f32x16 b2c = load_bias16(b2s + fo*32, half);
#pragma unroll
    for (int bt = 0; bt < 2; ++bt)
      acc[fo][bt] = __builtin_amdgcn_mfma_f32_32x32x16_fp8_fp8(
                      w2f[0][fo], hb[bt][0], b2c, 0,0,0);
  }
#pragma unroll
  for (int kt = 1; kt < 8; ++kt)
#pragma unroll
    for (int fo = 0; fo < 4; ++fo)
#pragma unroll
      for (int bt = 0; bt < 2; ++bt)
        acc[fo][bt] = __builtin_amdgcn_mfma_f32_32x32x16_fp8_fp8(
                        w2f[kt][fo], hb[bt][kt], acc[fo][bt], 0,0,0);

  // epilogue via MFMA: he = fp8(relu(512*h3)); u' = sum_k (64wf)_k * he_k
#pragma unroll
  for (int fo = 0; fo < 4; ++fo)
#pragma unroll
    for (int bt = 0; bt < 2; ++bt){
      hb[bt][fo*2+0] = c2b_kt<0>(acc[fo][bt]);
      hb[bt][fo*2+1] = c2b_kt<1>(acc[fo][bt]);
    }
  float bfv = bf[i];
  const int slot_i = ((i>>4)<<3) | (i&7);
#pragma unroll
  for (int bt = 0; bt < 2; ++bt){
    f32x16 a3;
#pragma unroll
    for (int q = 0; q < 16; ++q) a3[q] = 0.f;
#pragma unroll
    for (int kt = 0; kt < 8; ++kt)
      a3 = __builtin_amdgcn_mfma_f32_32x32x16_fp8_fp8(cur.wfa[kt], hb[bt][kt], a3, 0,0,0);
    // D[0, col] lives in element 0 of half0 lanes
    float u = a3[0];
    float ush = __shfl_xor(u, 32, 64);
    float uu = half ? ush : u;
    float val = 1.f/(1.f + __expf(-(uu*(1.f/32768.f) + bfv)));
#pragma unroll
    for (int s = 0; s < 16; ++s)
      if (s == slot_i)
        st[bt][s] = hm ? val : st[bt][s];
  }
}

// ---- main kernel: 1024 blocks x 64 threads; wave owns 64 rows; 1 wave/SIMD ----
__global__ void __launch_bounds__(64, 1)
genkern(const float* __restrict__ x, const float* __restrict__ z,
        const float* __restrict__ bf,
        const unsigned char* __restrict__ wip, const unsigned char* __restrict__ w1p,
        const unsigned char* __restrict__ w2p, const unsigned char* __restrict__ wfp,
        const float* __restrict__ Mt, const float* __restrict__ bi8,
        const float* __restrict__ b1s, const float* __restrict__ b2s,
        float* __restrict__ out)
{
  const int lane = (int)threadIdx.x;
  const int half = lane >> 5, col = lane & 31;
  const long rbase = (long)blockIdx.x * 64;

  // resident weight frags (fp8): 8 kt x 4 fo each
  long w1f[8][4], w2f[8][4];
#pragma unroll
  for (int kt = 0; kt < 8; ++kt)
#pragma unroll
    for (int fo = 0; fo < 4; ++fo){
      w1f[kt][fo] = *(const long*)(w1p + (((size_t)(kt*4+fo))*64 + lane)*8);
      w2f[kt][fo] = *(const long*)(w2p + (((size_t)(kt*4+fo))*64 + lane)*8);
    }

  // out-state: lane(half h) holds k = kt*16 + h*8 + j at slot kt*8+j, per bt
  float st[2][16];
#pragma unroll
  for (int bt = 0; bt < 2; ++bt)
#pragma unroll
    for (int kt = 0; kt < 2; ++kt)
      ld8(x + (rbase + bt*32 + col)*XD + kt*16 + half*8, &st[bt][kt*8]);

  Pref A, B;
  issue_pref(0, lane, rbase, col, wip, wfp, z, A);
  for (int ii = 0; ii < XD; ii += 2){
    stepfn(ii,   lane, half, col, rbase, Mt, bi8, b1s, b2s, bf, wip, wfp, z,
           w1f, w2f, st, A, B);
    stepfn(ii+1, lane, half, col, rbase, Mt, bi8, b1s, b2s, bf, wip, wfp, z,
           w1f, w2f, st, B, A);
  }

  // write out
#pragma unroll
  for (int bt = 0; bt < 2; ++bt)
#pragma unroll
    for (int kt = 0; kt < 2; ++kt){
      float* p = out + (rbase + bt*32 + col)*XD + kt*16 + half*8;
      float4 a, b;
      a.x = st[bt][kt*8+0]; a.y = st[bt][kt*8+1]; a.z = st[bt][kt*8+2]; a.w = st[bt][kt*8+3];
      b.x = st[bt][kt*8+4]; b.y = st[bt][kt*8+5]; b.z = st[bt][kt*8+6]; b.w = st[bt][kt*8+7];
      *(float4*)p = a;
      *(float4*)(p+4) = b;
    }
}

extern "C" void kernel_launch(void* const* d_in, const int* in_sizes, int n_in,
                              void* d_out, int out_size, void* d_ws, size_t ws_size,
                              hipStream_t stream){
  (void)in_sizes; (void)n_in; (void)out_size; (void)ws_size;
  const float* x  = (const float*)d_in[0];
  const float* z  = (const float*)d_in[1];
  const float* M  = (const float*)d_in[2];
  const float* Wi = (const float*)d_in[3];
  const float* bi = (const float*)d_in[4];
  const float* wf = (const float*)d_in[5];
  const float* bf = (const float*)d_in[6];
  const float* W1 = (const float*)d_in[7];
  const float* b1 = (const float*)d_in[8];
  const float* W2 = (const float*)d_in[9];
  const float* b2 = (const float*)d_in[10];

  unsigned char* wip = (unsigned char*)d_ws;            // 256*512 = 131072
  unsigned char* w1p = wip + 131072;                    // 32*512 = 16384
  unsigned char* w2p = w1p + 16384;                     // 16384
  unsigned char* wfp = w2p + 16384;                     // 256*512 = 131072
  float*         Mt  = (float*)(wfp + 131072);          // 4096
  float*         bi8 = Mt + 1024;                       // 16384
  float*         b1s = bi8 + 4096;                      // 512
  float*         b2s = b1s + 128;                       // 512

  prep<<<dim3(578), dim3(64), 0, stream>>>(Wi, bi, W1, b1, W2, b2, M, wf,
                                           wip, w1p, w2p, wfp, Mt, bi8, b1s, b2s);
  genkern<<<dim3(1024), dim3(64), 0, stream>>>(x, z, bf, wip, w1p, w2p, wfp, Mt,
                                               bi8, b1s, b2s, (float*)d_out);
}